// Round 1
// baseline (5069.825 us; speedup 1.0000x reference)
//
#include <hip/hip_runtime.h>
#include <math.h>

#define B_ 4
#define T_ 512
#define D_ 1024
#define H_ 16
#define DK_ 64
#define DV_ 64
#define R_ 32
#define GLR_ 64
#define INTER_ 3584
#define BT_ (B_*T_)
#define BTD_ (BT_*D_)
#define EPS_ 1e-5f

// ---------------- block reduction helper (256 threads) ----------------
__device__ __forceinline__ float block_sum256(float v) {
    __shared__ float red[4];
    #pragma unroll
    for (int o = 32; o > 0; o >>= 1) v += __shfl_down(v, o);
    __syncthreads();                       // protect red[] from previous use
    if ((threadIdx.x & 63) == 0) red[threadIdx.x >> 6] = v;
    __syncthreads();
    return red[0] + red[1] + red[2] + red[3];
}

// ---------------- LayerNorm kernels ----------------
// res = LN(query)*gp+bp ; q0 = LN(res)*gq+bq     (one block per token row)
__global__ void ln2_k(const float* __restrict__ x,
                      const float* __restrict__ gp, const float* __restrict__ bp,
                      const float* __restrict__ gq, const float* __restrict__ bq,
                      float* __restrict__ res, float* __restrict__ q0) {
    int bt = blockIdx.x, tid = threadIdx.x;
    float xv[4];
    #pragma unroll
    for (int i = 0; i < 4; i++) xv[i] = x[bt*D_ + tid + 256*i];
    float m = block_sum256(xv[0]+xv[1]+xv[2]+xv[3]) * (1.f/D_);
    float vs = 0.f;
    #pragma unroll
    for (int i = 0; i < 4; i++) { float d = xv[i]-m; vs += d*d; }
    float var = block_sum256(vs) * (1.f/D_);
    float rs = rsqrtf(var + EPS_);
    float r[4];
    #pragma unroll
    for (int i = 0; i < 4; i++) {
        int d = tid + 256*i;
        r[i] = (xv[i]-m)*rs*gp[d] + bp[d];
        res[bt*D_ + d] = r[i];
    }
    m = block_sum256(r[0]+r[1]+r[2]+r[3]) * (1.f/D_);
    vs = 0.f;
    #pragma unroll
    for (int i = 0; i < 4; i++) { float d = r[i]-m; vs += d*d; }
    var = block_sum256(vs) * (1.f/D_);
    rs = rsqrtf(var + EPS_);
    #pragma unroll
    for (int i = 0; i < 4; i++) {
        int d = tid + 256*i;
        q0[bt*D_ + d] = (r[i]-m)*rs*gq[d] + bq[d];
    }
}

// y = LN(x)*g+b
__global__ void ln_k(const float* __restrict__ x,
                     const float* __restrict__ g, const float* __restrict__ b,
                     float* __restrict__ y) {
    int bt = blockIdx.x, tid = threadIdx.x;
    float xv[4];
    #pragma unroll
    for (int i = 0; i < 4; i++) xv[i] = x[bt*D_ + tid + 256*i];
    float m = block_sum256(xv[0]+xv[1]+xv[2]+xv[3]) * (1.f/D_);
    float vs = 0.f;
    #pragma unroll
    for (int i = 0; i < 4; i++) { float d = xv[i]-m; vs += d*d; }
    float var = block_sum256(vs) * (1.f/D_);
    float rs = rsqrtf(var + EPS_);
    #pragma unroll
    for (int i = 0; i < 4; i++) {
        int d = tid + 256*i;
        y[bt*D_ + d] = (xv[i]-m)*rs*g[d] + b[d];
    }
}

// ---------------- elementwise kernels ----------------
// dd = tshift(x)-x ; z = x + dd*mu
__global__ void shift_lerp_k(const float* __restrict__ x, const float* __restrict__ mu,
                             float* __restrict__ dd, float* __restrict__ z) {
    int i = blockIdx.x*blockDim.x + threadIdx.x;
    int stride = gridDim.x*blockDim.x;
    for (; i < BTD_; i += stride) {
        int d = i & (D_-1);
        int t = (i >> 10) & (T_-1);
        float xv = x[i];
        float pv = (t == 0) ? 0.f : x[i - D_];
        float del = pv - xv;
        dd[i] = del;
        z[i] = fmaf(del, mu[d], xv);
    }
}

// z = x + dd*mu (dd already computed)
__global__ void lerp_dd_k(const float* __restrict__ x, const float* __restrict__ dd,
                          const float* __restrict__ mu, float* __restrict__ z) {
    int i = blockIdx.x*blockDim.x + threadIdx.x;
    int stride = gridDim.x*blockDim.x;
    for (; i < BTD_; i += stride)
        z[i] = fmaf(dd[i], mu[i & (D_-1)], x[i]);
}

// c = a + b
__global__ void add_k(const float* __restrict__ a, const float* __restrict__ b,
                      float* __restrict__ c) {
    int i = blockIdx.x*blockDim.x + threadIdx.x;
    int stride = gridDim.x*blockDim.x;
    for (; i < BTD_; i += stride) c[i] = a[i] + b[i];
}

// out = res2 + rec*vv
__global__ void final_k(const float* __restrict__ res2, const float* __restrict__ rec,
                        const float* __restrict__ vv, float* __restrict__ out) {
    int i = blockIdx.x*blockDim.x + threadIdx.x;
    int stride = gridDim.x*blockDim.x;
    for (; i < BTD_; i += stride) out[i] = fmaf(rec[i], vv[i], res2[i]);
}

// z[bt,d] = x[bt,d] + dd[bt,d] * ( sum_r low[bt,n,r]*x_w2[d,n,r] + x_bias[n,d] )
__global__ void zmake_k(const float* __restrict__ x, const float* __restrict__ dd,
                        const float* __restrict__ low, const float* __restrict__ w2,
                        const float* __restrict__ xb, float* __restrict__ z, int n) {
    int bt = blockIdx.x, tid = threadIdx.x;
    __shared__ float lo[R_];
    if (tid < R_) lo[tid] = low[bt*160 + n*R_ + tid];
    __syncthreads();
    #pragma unroll
    for (int q = 0; q < 4; q++) {
        int d = tid + 256*q;
        const float4* w4 = (const float4*)(w2 + (size_t)d*160 + n*R_);
        float acc = xb[n*D_ + d];
        #pragma unroll
        for (int rr = 0; rr < 8; rr++) {
            float4 wv = w4[rr];
            acc = fmaf(lo[rr*4+0], wv.x, acc);
            acc = fmaf(lo[rr*4+1], wv.y, acc);
            acc = fmaf(lo[rr*4+2], wv.z, acc);
            acc = fmaf(lo[rr*4+3], wv.w, acc);
        }
        int idx = bt*D_ + d;
        z[idx] = fmaf(dd[idx], acc, x[idx]);
    }
}

// ---------------- GEMM: C[M,N] = act(A[M,K] @ W[K,N] + bias) ----------------
// 64x64 tile, 256 threads, 4x4 microtile. ACT: 0 none, 1 tanh, 2 sigmoid, 3 sqrelu
template<int ACT>
__global__ __launch_bounds__(256) void gemm_k(const float* __restrict__ A,
                                              const float* __restrict__ W,
                                              float* __restrict__ C,
                                              int M, int N, int K,
                                              const float* __restrict__ bias) {
    __shared__ float As[16][65];   // [k][m], +1 pad to kill write conflicts
    __shared__ float Ws[16][64];   // [k][n]
    int tid = threadIdx.x;
    int tx = tid & 15, ty = tid >> 4;
    int row0 = blockIdx.y << 6, col0 = blockIdx.x << 6;
    int ka = tid & 15, ma = tid >> 4;     // A-load coords
    int nb = tid & 63, kb0 = tid >> 6;    // W-load coords
    float acc[4][4] = {};
    for (int k0 = 0; k0 < K; k0 += 16) {
        #pragma unroll
        for (int i = 0; i < 4; i++) {
            int rr = row0 + ma + 16*i;
            As[ka][ma + 16*i] = (rr < M) ? A[(size_t)rr*K + k0 + ka] : 0.f;
        }
        #pragma unroll
        for (int i = 0; i < 4; i++) {
            int cc = col0 + nb;
            Ws[kb0 + 4*i][nb] = (cc < N) ? W[(size_t)(k0 + kb0 + 4*i)*N + cc] : 0.f;
        }
        __syncthreads();
        #pragma unroll
        for (int kk = 0; kk < 16; kk++) {
            float a[4], bv[4];
            #pragma unroll
            for (int i = 0; i < 4; i++) a[i] = As[kk][ty + 16*i];
            #pragma unroll
            for (int j = 0; j < 4; j++) bv[j] = Ws[kk][tx + 16*j];
            #pragma unroll
            for (int i = 0; i < 4; i++)
                #pragma unroll
                for (int j = 0; j < 4; j++)
                    acc[i][j] = fmaf(a[i], bv[j], acc[i][j]);
        }
        __syncthreads();
    }
    #pragma unroll
    for (int i = 0; i < 4; i++) {
        int rr = row0 + ty + 16*i;
        if (rr >= M) continue;
        #pragma unroll
        for (int j = 0; j < 4; j++) {
            int cc = col0 + tx + 16*j;
            if (cc >= N) continue;
            float xv = acc[i][j];
            if (bias) xv += bias[cc];
            if (ACT == 1) xv = tanhf(xv);
            else if (ACT == 2) xv = 1.f / (1.f + __expf(-xv));
            else if (ACT == 3) { xv = fmaxf(xv, 0.f); xv = xv*xv; }
            C[(size_t)rr*N + cc] = xv;
        }
    }
}

// ---------------- WKV6 linear-attention scan ----------------
// grid = B*H*4 (16 v-columns per block), block = 64 (lane = kg*16+vi, k split 4x16)
__global__ void wkv6_k(const float* __restrict__ r, const float* __restrict__ k,
                       const float* __restrict__ v, const float* __restrict__ w,
                       const float* __restrict__ u, float* __restrict__ o) {
    int bid = blockIdx.x;
    int vc = bid & 3;
    int h  = (bid >> 2) & (H_-1);
    int b  = bid >> 6;
    int l  = threadIdx.x;
    int vi = l & 15, kg = l >> 4;
    int vcol = vc*16 + vi;
    float uv = u[h*DK_ + l];          // u[h][k=l]
    float S[16];
    #pragma unroll
    for (int i = 0; i < 16; i++) S[i] = 0.f;
    int base = b*T_*D_ + h*DK_;
    int srcbase = l & 48;
    for (int t = 0; t < T_; t++) {
        int off = base + t*D_;
        float rv  = r[off + l];
        float kv_ = k[off + l];
        float wv  = w[off + l];
        float vt  = v[off + vcol];
        float ev  = __expf(-__expf(wv));     // decay = exp(-exp(w_raw))
        float rav = rv * uv * kv_;
        #pragma unroll
        for (int ofs = 32; ofs > 0; ofs >>= 1) rav += __shfl_xor(rav, ofs);
        float oacc = 0.f;
        #pragma unroll
        for (int i = 0; i < 16; i++) {
            float ri = __shfl(rv,  srcbase + i);
            float ki = __shfl(kv_, srcbase + i);
            float ei = __shfl(ev,  srcbase + i);
            oacc = fmaf(ri, S[i], oacc);     // uses pre-update state
            S[i] = fmaf(ei, S[i], ki * vt);
        }
        oacc += __shfl_xor(oacc, 16);
        oacc += __shfl_xor(oacc, 32);
        if (kg == 0) o[off + vcol] = fmaf(rav, vt, oacc);
    }
}

// ---------------- per-head GroupNorm * swish(gate) ----------------
// grid = BT*H, block = 64
__global__ void gn_gate_k(const float* __restrict__ o, const float* __restrict__ g,
                          const float* __restrict__ gng, const float* __restrict__ gnb,
                          float* __restrict__ out) {
    int bid = blockIdx.x;
    int h = bid & (H_-1);
    int bt = bid >> 4;
    int l = threadIdx.x;
    int idx = bt*D_ + h*DV_ + l;
    float x = o[idx];
    float s = x;
    #pragma unroll
    for (int ofs = 32; ofs > 0; ofs >>= 1) s += __shfl_xor(s, ofs);
    float m = s * (1.f/DV_);
    float dv = x - m;
    float v2 = dv*dv;
    #pragma unroll
    for (int ofs = 32; ofs > 0; ofs >>= 1) v2 += __shfl_xor(v2, ofs);
    float var = v2 * (1.f/DV_);
    float xn = dv * rsqrtf(var + EPS_);
    int d = h*DV_ + l;
    float gg = g[idx];
    float sw = gg / (1.f + __expf(-gg));
    out[idx] = (xn * gng[d] + gnb[d]) * sw;
}

// ---------------- host ----------------
extern "C" void kernel_launch(void* const* d_in, const int* in_sizes, int n_in,
                              void* d_out, int out_size, void* d_ws, size_t ws_size,
                              hipStream_t stream) {
    const float* const* in = (const float* const*)d_in;
    const float* query  = in[0];
    const float* keyval = in[1];
    const float* lnp_g = in[2]; const float* lnp_b = in[3];
    const float* lnq_g = in[4]; const float* lnq_b = in[5];
    const float* lnkv_g = in[6]; const float* lnkv_b = in[7];
    const float* lnf_g = in[8]; const float* lnf_b = in[9];
    float* out = (float*)d_out;

    // workspace carve (floats)
    float* p = (float*)d_ws;
    float* res = p;  p += BTD_;
    float* kv0 = p;  p += BTD_;
    float* xa  = p;  p += BTD_;
    float* xb  = p;  p += BTD_;
    float* dd  = p;  p += BTD_;
    float* z   = p;  p += BTD_;
    float* rbf = p;  p += BTD_;
    float* kbf = p;  p += BTD_;   // kbf..wbf contiguous: aliased as FFN inter buffer
    float* vbf = p;  p += BTD_;
    float* gbf = p;  p += BTD_;
    float* wbf = p;  p += BTD_;
    float* obf = p;  p += BTD_;
    float* lowb  = p; p += BT_*160;
    float* wlowb = p; p += BT_*GLR_;
    float* kkb = kbf;             // [BT, INTER] = 7.34M floats <= 8.39M ok

    auto gemm = [&](const float* A, const float* W, float* C, int M, int N, int K,
                    int act, const float* bias) {
        dim3 g((N + 63) / 64, (M + 63) / 64);
        if (act == 0)      gemm_k<0><<<g, 256, 0, stream>>>(A, W, C, M, N, K, bias);
        else if (act == 1) gemm_k<1><<<g, 256, 0, stream>>>(A, W, C, M, N, K, bias);
        else if (act == 2) gemm_k<2><<<g, 256, 0, stream>>>(A, W, C, M, N, K, bias);
        else               gemm_k<3><<<g, 256, 0, stream>>>(A, W, C, M, N, K, bias);
    };

    // front layernorms: res = LN(query); xa = LN(res); kv0 = LN(keyval)
    ln2_k<<<BT_, 256, 0, stream>>>(query, lnp_g, lnp_b, lnq_g, lnq_b, res, xa);
    ln_k<<<BT_, 256, 0, stream>>>(keyval, lnkv_g, lnkv_b, kv0);

    auto run_attn = [&](const float* xq, const float* xkv, bool self_mode, int pb,
                        float* attn_out) {
        const float* x_mu  = in[pb+0];  const float* x_w1  = in[pb+1];
        const float* x_w2  = in[pb+2];  const float* x_bias= in[pb+3];
        const float* r_w   = in[pb+4];  const float* k_w   = in[pb+5];
        const float* v_w   = in[pb+6];  const float* g_w   = in[pb+7];
        const float* w_a   = in[pb+8];  const float* w_b   = in[pb+9];
        const float* w_bias= in[pb+10]; const float* u     = in[pb+11];
        const float* gn_g  = in[pb+12]; const float* gn_b  = in[pb+13];
        const float* o_w   = in[pb+14];

        // q-side mus -> r, g projections
        shift_lerp_k<<<1024, 256, 0, stream>>>(xq, x_mu, dd, z);
        gemm(z, x_w1, lowb, BT_, 160, D_, 1, nullptr);
        zmake_k<<<BT_, 256, 0, stream>>>(xq, dd, lowb, x_w2, x_bias, z, 0);
        gemm(z, r_w, rbf, BT_, D_, D_, 0, nullptr);
        zmake_k<<<BT_, 256, 0, stream>>>(xq, dd, lowb, x_w2, x_bias, z, 4);
        gemm(z, g_w, gbf, BT_, D_, D_, 0, nullptr);
        // kv-side mus -> w, k, v projections
        const float* xs = xq;
        if (!self_mode) {
            shift_lerp_k<<<1024, 256, 0, stream>>>(xkv, x_mu, dd, z);
            gemm(z, x_w1, lowb, BT_, 160, D_, 1, nullptr);
            xs = xkv;
        }
        zmake_k<<<BT_, 256, 0, stream>>>(xs, dd, lowb, x_w2, x_bias, z, 1);
        gemm(z, w_a, wlowb, BT_, GLR_, D_, 1, nullptr);
        gemm(wlowb, w_b, wbf, BT_, D_, GLR_, 0, w_bias);
        zmake_k<<<BT_, 256, 0, stream>>>(xs, dd, lowb, x_w2, x_bias, z, 2);
        gemm(z, k_w, kbf, BT_, D_, D_, 0, nullptr);
        zmake_k<<<BT_, 256, 0, stream>>>(xs, dd, lowb, x_w2, x_bias, z, 3);
        gemm(z, v_w, vbf, BT_, D_, D_, 0, nullptr);
        // scan + groupnorm/gate + out proj
        wkv6_k<<<B_*H_*4, 64, 0, stream>>>(rbf, kbf, vbf, wbf, u, obf);
        gn_gate_k<<<BT_*H_, 64, 0, stream>>>(obf, gbf, gn_g, gn_b, z);
        gemm(z, o_w, attn_out, BT_, D_, D_, 0, nullptr);
    };

    run_attn(xa, xa, true, 10, xb);      // self time-mix: xa -> xb
    run_attn(xb, kv0, false, 25, xa);    // cross time-mix: xb -> xa

    add_k<<<1024, 256, 0, stream>>>(xa, res, xb);          // res2 -> xb
    ln_k<<<BT_, 256, 0, stream>>>(xb, lnf_g, lnf_b, xa);   // ffn input -> xa

    shift_lerp_k<<<1024, 256, 0, stream>>>(xa, in[40], dd, z);       // mu_k lerp
    gemm(z, in[41], kkb, BT_, INTER_, D_, 3, nullptr);               // sqrelu key
    gemm(kkb, in[42], obf, BT_, D_, INTER_, 0, nullptr);             // value
    lerp_dd_k<<<1024, 256, 0, stream>>>(xa, dd, in[43], z);          // mu_r lerp
    gemm(z, in[44], rbf, BT_, D_, D_, 2, nullptr);                   // sigmoid rec
    final_k<<<1024, 256, 0, stream>>>(xb, rbf, obf, out);            // res2 + rec*vv
}

// Round 2
// 2638.620 us; speedup vs baseline: 1.9214x; 1.9214x over previous
//
#include <hip/hip_runtime.h>
#include <math.h>

#define B_ 4
#define T_ 512
#define D_ 1024
#define H_ 16
#define DK_ 64
#define DV_ 64
#define R_ 32
#define GLR_ 64
#define INTER_ 3584
#define BT_ (B_*T_)
#define BTD_ (BT_*D_)
#define EPS_ 1e-5f

typedef short short8 __attribute__((ext_vector_type(8)));
typedef float f32x4 __attribute__((ext_vector_type(4)));

__device__ __forceinline__ unsigned short cvt_bf16(float f) {
    unsigned u = __float_as_uint(f);
    return (unsigned short)((u + 0x7FFFu + ((u >> 16) & 1u)) >> 16);
}

// ---------------- block reduction helper (256 threads) ----------------
__device__ __forceinline__ float block_sum256(float v) {
    __shared__ float red[4];
    #pragma unroll
    for (int o = 32; o > 0; o >>= 1) v += __shfl_down(v, o);
    __syncthreads();
    if ((threadIdx.x & 63) == 0) red[threadIdx.x >> 6] = v;
    __syncthreads();
    return red[0] + red[1] + red[2] + red[3];
}

// ---------------- LayerNorm kernels ----------------
__global__ void ln2_k(const float* __restrict__ x,
                      const float* __restrict__ gp, const float* __restrict__ bp,
                      const float* __restrict__ gq, const float* __restrict__ bq,
                      float* __restrict__ res, float* __restrict__ q0) {
    int bt = blockIdx.x, tid = threadIdx.x;
    float xv[4];
    #pragma unroll
    for (int i = 0; i < 4; i++) xv[i] = x[bt*D_ + tid + 256*i];
    float m = block_sum256(xv[0]+xv[1]+xv[2]+xv[3]) * (1.f/D_);
    float vs = 0.f;
    #pragma unroll
    for (int i = 0; i < 4; i++) { float d = xv[i]-m; vs += d*d; }
    float var = block_sum256(vs) * (1.f/D_);
    float rs = rsqrtf(var + EPS_);
    float r[4];
    #pragma unroll
    for (int i = 0; i < 4; i++) {
        int d = tid + 256*i;
        r[i] = (xv[i]-m)*rs*gp[d] + bp[d];
        res[bt*D_ + d] = r[i];
    }
    m = block_sum256(r[0]+r[1]+r[2]+r[3]) * (1.f/D_);
    vs = 0.f;
    #pragma unroll
    for (int i = 0; i < 4; i++) { float d = r[i]-m; vs += d*d; }
    var = block_sum256(vs) * (1.f/D_);
    rs = rsqrtf(var + EPS_);
    #pragma unroll
    for (int i = 0; i < 4; i++) {
        int d = tid + 256*i;
        q0[bt*D_ + d] = (r[i]-m)*rs*gq[d] + bq[d];
    }
}

__global__ void ln_k(const float* __restrict__ x,
                     const float* __restrict__ g, const float* __restrict__ b,
                     float* __restrict__ y) {
    int bt = blockIdx.x, tid = threadIdx.x;
    float xv[4];
    #pragma unroll
    for (int i = 0; i < 4; i++) xv[i] = x[bt*D_ + tid + 256*i];
    float m = block_sum256(xv[0]+xv[1]+xv[2]+xv[3]) * (1.f/D_);
    float vs = 0.f;
    #pragma unroll
    for (int i = 0; i < 4; i++) { float d = xv[i]-m; vs += d*d; }
    float var = block_sum256(vs) * (1.f/D_);
    float rs = rsqrtf(var + EPS_);
    #pragma unroll
    for (int i = 0; i < 4; i++) {
        int d = tid + 256*i;
        y[bt*D_ + d] = (xv[i]-m)*rs*g[d] + b[d];
    }
}

// ---------------- elementwise kernels ----------------
// dd = tshift(x)-x ; z(bf16) = x + dd*mu
__global__ void shift_lerp_k(const float* __restrict__ x, const float* __restrict__ mu,
                             float* __restrict__ dd, unsigned short* __restrict__ z) {
    int i = blockIdx.x*blockDim.x + threadIdx.x;
    int stride = gridDim.x*blockDim.x;
    for (; i < BTD_; i += stride) {
        int d = i & (D_-1);
        int t = (i >> 10) & (T_-1);
        float xv = x[i];
        float pv = (t == 0) ? 0.f : x[i - D_];
        float del = pv - xv;
        dd[i] = del;
        z[i] = cvt_bf16(fmaf(del, mu[d], xv));
    }
}

__global__ void lerp_dd_k(const float* __restrict__ x, const float* __restrict__ dd,
                          const float* __restrict__ mu, unsigned short* __restrict__ z) {
    int i = blockIdx.x*blockDim.x + threadIdx.x;
    int stride = gridDim.x*blockDim.x;
    for (; i < BTD_; i += stride)
        z[i] = cvt_bf16(fmaf(dd[i], mu[i & (D_-1)], x[i]));
}

__global__ void add_k(const float* __restrict__ a, const float* __restrict__ b,
                      float* __restrict__ c) {
    int i = blockIdx.x*blockDim.x + threadIdx.x;
    int stride = gridDim.x*blockDim.x;
    for (; i < BTD_; i += stride) c[i] = a[i] + b[i];
}

__global__ void final_k(const float* __restrict__ res2, const float* __restrict__ rec,
                        const float* __restrict__ vv, float* __restrict__ out) {
    int i = blockIdx.x*blockDim.x + threadIdx.x;
    int stride = gridDim.x*blockDim.x;
    for (; i < BTD_; i += stride) out[i] = fmaf(rec[i], vv[i], res2[i]);
}

// z(bf16)[bt,d] = x + dd * ( sum_r low[bt,n,r]*x_w2[d,n,r] + x_bias[n,d] )
__global__ void zmake_k(const float* __restrict__ x, const float* __restrict__ dd,
                        const float* __restrict__ low, const float* __restrict__ w2,
                        const float* __restrict__ xb, unsigned short* __restrict__ z, int n) {
    int bt = blockIdx.x, tid = threadIdx.x;
    __shared__ float lo[R_];
    if (tid < R_) lo[tid] = low[bt*256 + n*R_ + tid];
    __syncthreads();
    #pragma unroll
    for (int q = 0; q < 4; q++) {
        int d = tid + 256*q;
        const float4* w4 = (const float4*)(w2 + (size_t)d*160 + n*R_);
        float acc = xb[n*D_ + d];
        #pragma unroll
        for (int rr = 0; rr < 8; rr++) {
            float4 wv = w4[rr];
            acc = fmaf(lo[rr*4+0], wv.x, acc);
            acc = fmaf(lo[rr*4+1], wv.y, acc);
            acc = fmaf(lo[rr*4+2], wv.z, acc);
            acc = fmaf(lo[rr*4+3], wv.w, acc);
        }
        int idx = bt*D_ + d;
        z[idx] = cvt_bf16(fmaf(dd[idx], acc, x[idx]));
    }
}

// ---------------- weight convert+transpose: src[K,N] f32 -> dst[Np][Kp] bf16 ----------------
__global__ void cw_k(const float* __restrict__ src, unsigned short* __restrict__ dst,
                     int K, int N, int Kp) {
    __shared__ unsigned short t[64][65];
    int n0 = blockIdx.x << 6, k0 = blockIdx.y << 6;
    int tid = threadIdx.x;
    int jn = tid & 63, si = tid >> 6;
    #pragma unroll
    for (int s = 0; s < 16; s++) {
        int kl = si*16 + s;
        int k = k0 + kl, n = n0 + jn;
        float v = (k < K && n < N) ? src[(size_t)k*N + n] : 0.f;
        t[jn][kl] = cvt_bf16(v);
    }
    __syncthreads();
    #pragma unroll
    for (int s = 0; s < 16; s++) {
        int nl = si*16 + s;
        dst[(size_t)(n0 + nl)*Kp + k0 + jn] = t[nl][jn];
    }
}

// ---------------- bf16 MFMA GEMM: C[M,N] = act(A[M,K] @ Bt[N,K]^T + bias) ----------------
// BM=64 BN=128 BK=64, 256 threads = 4 waves (2x2), per-wave 32x64, acc 2x4 frags.
// LDS linear rows of 128B, XOR-swizzled 16B slots (slot ^= row&7); source pre-swizzled.
template<int ACT, int OBF>
__global__ __launch_bounds__(256) void mgemm_k(
        const unsigned short* __restrict__ A, const unsigned short* __restrict__ Bt,
        float* __restrict__ C, unsigned short* __restrict__ Cb,
        int N, int K, const float* __restrict__ bias) {
    __shared__ __align__(16) unsigned short Al[64*64];
    __shared__ __align__(16) unsigned short Bl[128*64];
    const int tid = threadIdx.x;
    const int w = tid >> 6, l = tid & 63;
    const int wr = w >> 1, wc = w & 1;
    const int row0 = blockIdx.y << 6, col0 = blockIdx.x << 7;
    f32x4 acc[2][4] = {};

    const unsigned short* aptr[2];
    const unsigned short* bptr[4];
    #pragma unroll
    for (int c = 0; c < 2; c++) {
        int off = c*4096 + tid*16;
        int row = off >> 7;
        int kg = ((off >> 4) & 7) ^ (row & 7);
        aptr[c] = A + (size_t)(row0 + row)*K + kg*8;
    }
    #pragma unroll
    for (int c = 0; c < 4; c++) {
        int off = c*4096 + tid*16;
        int row = off >> 7;
        int kg = ((off >> 4) & 7) ^ (row & 7);
        bptr[c] = Bt + (size_t)(col0 + row)*K + kg*8;
    }

    for (int k0 = 0; k0 < K; k0 += 64) {
        uint4 sa[2], sb[4];
        #pragma unroll
        for (int c = 0; c < 2; c++) { sa[c] = *(const uint4*)aptr[c]; aptr[c] += 64; }
        #pragma unroll
        for (int c = 0; c < 4; c++) { sb[c] = *(const uint4*)bptr[c]; bptr[c] += 64; }
        __syncthreads();   // all waves done reading LDS of prev iter
        #pragma unroll
        for (int c = 0; c < 2; c++) *(uint4*)&Al[c*2048 + tid*8] = sa[c];
        #pragma unroll
        for (int c = 0; c < 4; c++) *(uint4*)&Bl[c*2048 + tid*8] = sb[c];
        __syncthreads();   // tile ready

        short8 af[2][2], bfr[4][2];
        #pragma unroll
        for (int m = 0; m < 2; m++)
        #pragma unroll
        for (int kk = 0; kk < 2; kk++) {
            int row = wr*32 + m*16 + (l & 15);
            int kg = kk*4 + (l >> 4);
            af[m][kk] = *(const short8*)&Al[row*64 + ((kg ^ (row & 7)) << 3)];
        }
        #pragma unroll
        for (int n = 0; n < 4; n++)
        #pragma unroll
        for (int kk = 0; kk < 2; kk++) {
            int row = wc*64 + n*16 + (l & 15);
            int kg = kk*4 + (l >> 4);
            bfr[n][kk] = *(const short8*)&Bl[row*64 + ((kg ^ (row & 7)) << 3)];
        }
        #pragma unroll
        for (int kk = 0; kk < 2; kk++)
        #pragma unroll
        for (int m = 0; m < 2; m++)
        #pragma unroll
        for (int n = 0; n < 4; n++)
            asm volatile("v_mfma_f32_16x16x32_bf16 %0, %1, %2, %0"
                         : "+v"(acc[m][n]) : "v"(af[m][kk]), "v"(bfr[n][kk]));
    }
    // MFMA -> VALU read hazard guard
    asm volatile("s_nop 7\n\ts_nop 7\n\ts_nop 7");

    const int erow = row0 + wr*32 + (l >> 4)*4;
    const int ecol = col0 + wc*64 + (l & 15);
    #pragma unroll
    for (int m = 0; m < 2; m++)
    #pragma unroll
    for (int n = 0; n < 4; n++) {
        float bv = (bias != nullptr) ? bias[ecol + n*16] : 0.f;
        #pragma unroll
        for (int q = 0; q < 4; q++) {
            float x = acc[m][n][q] + bv;
            if (ACT == 1) x = tanhf(x);
            else if (ACT == 2) x = 1.f / (1.f + __expf(-x));
            else if (ACT == 3) { x = fmaxf(x, 0.f); x = x * x; }
            size_t idx = (size_t)(erow + m*16 + q) * N + (ecol + n*16);
            if (OBF) Cb[idx] = cvt_bf16(x);
            else     C[idx] = x;
        }
    }
}

// ---------------- WKV6 linear-attention scan ----------------
__global__ void wkv6_k(const float* __restrict__ r, const float* __restrict__ k,
                       const float* __restrict__ v, const float* __restrict__ w,
                       const float* __restrict__ u, float* __restrict__ o) {
    int bid = blockIdx.x;
    int vc = bid & 3;
    int h  = (bid >> 2) & (H_-1);
    int b  = bid >> 6;
    int l  = threadIdx.x;
    int vi = l & 15, kg = l >> 4;
    int vcol = vc*16 + vi;
    float uv = u[h*DK_ + l];
    float S[16];
    #pragma unroll
    for (int i = 0; i < 16; i++) S[i] = 0.f;
    int base = b*T_*D_ + h*DK_;
    int srcbase = l & 48;
    for (int t = 0; t < T_; t++) {
        int off = base + t*D_;
        float rv  = r[off + l];
        float kv_ = k[off + l];
        float wv  = w[off + l];
        float vt  = v[off + vcol];
        float ev  = __expf(-__expf(wv));
        float rav = rv * uv * kv_;
        #pragma unroll
        for (int ofs = 32; ofs > 0; ofs >>= 1) rav += __shfl_xor(rav, ofs);
        float oacc = 0.f;
        #pragma unroll
        for (int i = 0; i < 16; i++) {
            float ri = __shfl(rv,  srcbase + i);
            float ki = __shfl(kv_, srcbase + i);
            float ei = __shfl(ev,  srcbase + i);
            oacc = fmaf(ri, S[i], oacc);
            S[i] = fmaf(ei, S[i], ki * vt);
        }
        oacc += __shfl_xor(oacc, 16);
        oacc += __shfl_xor(oacc, 32);
        if (kg == 0) o[off + vcol] = fmaf(rav, vt, oacc);
    }
}

// ---------------- per-head GroupNorm * swish(gate), bf16 out ----------------
__global__ void gn_gate_k(const float* __restrict__ o, const float* __restrict__ g,
                          const float* __restrict__ gng, const float* __restrict__ gnb,
                          unsigned short* __restrict__ out) {
    int bid = blockIdx.x;
    int h = bid & (H_-1);
    int bt = bid >> 4;
    int l = threadIdx.x;
    int idx = bt*D_ + h*DV_ + l;
    float x = o[idx];
    float s = x;
    #pragma unroll
    for (int ofs = 32; ofs > 0; ofs >>= 1) s += __shfl_xor(s, ofs);
    float m = s * (1.f/DV_);
    float dv = x - m;
    float v2 = dv*dv;
    #pragma unroll
    for (int ofs = 32; ofs > 0; ofs >>= 1) v2 += __shfl_xor(v2, ofs);
    float var = v2 * (1.f/DV_);
    float xn = dv * rsqrtf(var + EPS_);
    int d = h*DV_ + l;
    float gg = g[idx];
    float sw = gg / (1.f + __expf(-gg));
    out[idx] = cvt_bf16((xn * gng[d] + gnb[d]) * sw);
}

// ---------------- host ----------------
extern "C" void kernel_launch(void* const* d_in, const int* in_sizes, int n_in,
                              void* d_out, int out_size, void* d_ws, size_t ws_size,
                              hipStream_t stream) {
    const float* const* in = (const float* const*)d_in;
    const float* query  = in[0];
    const float* keyval = in[1];
    const float* lnp_g = in[2]; const float* lnp_b = in[3];
    const float* lnq_g = in[4]; const float* lnq_b = in[5];
    const float* lnkv_g = in[6]; const float* lnkv_b = in[7];
    const float* lnf_g = in[8]; const float* lnf_b = in[9];
    float* out = (float*)d_out;

    // workspace carve (~94 MB)
    float* p = (float*)d_ws;
    float* res = p;  p += BTD_;
    float* xa  = p;  p += BTD_;
    float* xb  = p;  p += BTD_;
    float* dd  = p;  p += BTD_;
    float* rbf = p;  p += BTD_;
    float* kbf = p;  p += BTD_;
    float* vbf = p;  p += BTD_;
    float* gbf = p;  p += BTD_;
    float* wbf = p;  p += BTD_;
    float* obf = p;  p += BTD_;
    float* lowb = p; p += BT_*256;
    unsigned short* zb   = (unsigned short*)p;
    unsigned short* wlb  = zb + BTD_;
    unsigned short* wscr = wlb + BT_*128;
    unsigned short* kkbb = (unsigned short*)rbf;   // [BT,3584] bf16 over rbf+kbf (FFN only)

    auto cw = [&](const float* src, int K, int N, int Kp, int Np) {
        cw_k<<<dim3(Np >> 6, Kp >> 6), 256, 0, stream>>>(src, wscr, K, N, Kp);
    };
    auto mg = [&](const unsigned short* A, float* Cf, unsigned short* Cbf,
                  int N, int K, int act, const float* bias) {
        dim3 g(N >> 7, BT_ >> 6);
        if (act == 0)          mgemm_k<0,0><<<g,256,0,stream>>>(A, wscr, Cf, nullptr, N, K, bias);
        else if (act == 1 && !Cbf) mgemm_k<1,0><<<g,256,0,stream>>>(A, wscr, Cf, nullptr, N, K, bias);
        else if (act == 1)     mgemm_k<1,1><<<g,256,0,stream>>>(A, wscr, nullptr, Cbf, N, K, bias);
        else if (act == 2)     mgemm_k<2,0><<<g,256,0,stream>>>(A, wscr, Cf, nullptr, N, K, bias);
        else                   mgemm_k<3,1><<<g,256,0,stream>>>(A, wscr, nullptr, Cbf, N, K, bias);
    };

    ln2_k<<<BT_, 256, 0, stream>>>(query, lnp_g, lnp_b, lnq_g, lnq_b, res, xa);

    auto run_attn = [&](const float* xq, const float* xkv, bool self, int pb, float* outbuf) {
        const float* x_mu  = in[pb+0];  const float* x_w1  = in[pb+1];
        const float* x_w2  = in[pb+2];  const float* x_bias= in[pb+3];
        const float* r_w   = in[pb+4];  const float* k_w   = in[pb+5];
        const float* v_w   = in[pb+6];  const float* g_w   = in[pb+7];
        const float* w_a   = in[pb+8];  const float* w_b   = in[pb+9];
        const float* w_bias= in[pb+10]; const float* u     = in[pb+11];
        const float* gn_g  = in[pb+12]; const float* gn_b  = in[pb+13];
        const float* o_w   = in[pb+14];

        shift_lerp_k<<<1024, 256, 0, stream>>>(xq, x_mu, dd, zb);
        cw(x_w1, 1024, 160, 1024, 256);
        mg(zb, lowb, nullptr, 256, 1024, 1, nullptr);
        zmake_k<<<BT_, 256, 0, stream>>>(xq, dd, lowb, x_w2, x_bias, zb, 0);
        cw(r_w, 1024, 1024, 1024, 1024);
        mg(zb, rbf, nullptr, 1024, 1024, 0, nullptr);
        zmake_k<<<BT_, 256, 0, stream>>>(xq, dd, lowb, x_w2, x_bias, zb, 4);
        cw(g_w, 1024, 1024, 1024, 1024);
        mg(zb, gbf, nullptr, 1024, 1024, 0, nullptr);

        const float* xs = xq;
        if (!self) {
            shift_lerp_k<<<1024, 256, 0, stream>>>(xkv, x_mu, dd, zb);
            cw(x_w1, 1024, 160, 1024, 256);
            mg(zb, lowb, nullptr, 256, 1024, 1, nullptr);
            xs = xkv;
        }
        zmake_k<<<BT_, 256, 0, stream>>>(xs, dd, lowb, x_w2, x_bias, zb, 1);
        cw(w_a, 1024, 64, 1024, 128);
        mg(zb, nullptr, wlb, 128, 1024, 1, nullptr);            // tanh, bf16 out
        cw(w_b, 64, 1024, 128, 1024);
        mg(wlb, wbf, nullptr, 1024, 128, 0, w_bias);
        zmake_k<<<BT_, 256, 0, stream>>>(xs, dd, lowb, x_w2, x_bias, zb, 2);
        cw(k_w, 1024, 1024, 1024, 1024);
        mg(zb, kbf, nullptr, 1024, 1024, 0, nullptr);
        zmake_k<<<BT_, 256, 0, stream>>>(xs, dd, lowb, x_w2, x_bias, zb, 3);
        cw(v_w, 1024, 1024, 1024, 1024);
        mg(zb, vbf, nullptr, 1024, 1024, 0, nullptr);

        wkv6_k<<<B_*H_*4, 64, 0, stream>>>(rbf, kbf, vbf, wbf, u, obf);
        gn_gate_k<<<BT_*H_, 64, 0, stream>>>(obf, gbf, gn_g, gn_b, zb);
        cw(o_w, 1024, 1024, 1024, 1024);
        mg(zb, outbuf, nullptr, 1024, 1024, 0, nullptr);
    };

    run_attn(xa, xa, true, 10, xb);                      // self: xa -> xb
    ln_k<<<BT_, 256, 0, stream>>>(keyval, lnkv_g, lnkv_b, xa);   // kv0 -> xa
    run_attn(xb, xa, false, 25, xa);                     // cross: -> xa (written last)

    add_k<<<1024, 256, 0, stream>>>(xa, res, xb);        // res2 -> xb
    ln_k<<<BT_, 256, 0, stream>>>(xb, lnf_g, lnf_b, res);// ffn input -> res

    shift_lerp_k<<<1024, 256, 0, stream>>>(res, in[40], dd, zb);
    cw(in[41], 1024, 3584, 1024, 3584);
    mg(zb, nullptr, kkbb, 3584, 1024, 3, nullptr);       // sqrelu key, bf16
    cw(in[42], 3584, 1024, 3584, 1024);
    mg(kkbb, obf, nullptr, 1024, 3584, 0, nullptr);      // value
    lerp_dd_k<<<1024, 256, 0, stream>>>(res, dd, in[43], zb);
    cw(in[44], 1024, 1024, 1024, 1024);
    mg(zb, vbf, nullptr, 1024, 1024, 2, nullptr);        // sigmoid rec -> vbf
    final_k<<<1024, 256, 0, stream>>>(xb, vbf, obf, out);
}

// Round 4
// 1901.791 us; speedup vs baseline: 2.6658x; 1.3874x over previous
//
#include <hip/hip_runtime.h>
#include <math.h>

#define B_ 4
#define T_ 512
#define D_ 1024
#define H_ 16
#define DK_ 64
#define DV_ 64
#define R_ 32
#define GLR_ 64
#define INTER_ 3584
#define BT_ (B_*T_)
#define BTD_ (BT_*D_)
#define EPS_ 1e-5f

typedef short short8 __attribute__((ext_vector_type(8)));
typedef float f32x4 __attribute__((ext_vector_type(4)));

__device__ __forceinline__ unsigned short cvt_bf16(float f) {
    unsigned u = __float_as_uint(f);
    return (unsigned short)((u + 0x7FFFu + ((u >> 16) & 1u)) >> 16);
}

// async global->LDS, 16B per lane (dest = wave-uniform base + lane*16)
__device__ __forceinline__ void gload16(const unsigned short* g, unsigned short* l) {
    __builtin_amdgcn_global_load_lds(
        (const __attribute__((address_space(1))) void*)g,
        (__attribute__((address_space(3))) void*)l, 16, 0, 0);
}

// ---------------- block reduction helper (256 threads) ----------------
__device__ __forceinline__ float block_sum256(float v) {
    __shared__ float red[4];
    #pragma unroll
    for (int o = 32; o > 0; o >>= 1) v += __shfl_down(v, o);
    __syncthreads();
    if ((threadIdx.x & 63) == 0) red[threadIdx.x >> 6] = v;
    __syncthreads();
    return red[0] + red[1] + red[2] + red[3];
}

// ---------------- LayerNorm kernels ----------------
__global__ void ln2_k(const float* __restrict__ x,
                      const float* __restrict__ gp, const float* __restrict__ bp,
                      const float* __restrict__ gq, const float* __restrict__ bq,
                      float* __restrict__ res, float* __restrict__ q0) {
    int bt = blockIdx.x, tid = threadIdx.x;
    float xv[4];
    #pragma unroll
    for (int i = 0; i < 4; i++) xv[i] = x[bt*D_ + tid + 256*i];
    float m = block_sum256(xv[0]+xv[1]+xv[2]+xv[3]) * (1.f/D_);
    float vs = 0.f;
    #pragma unroll
    for (int i = 0; i < 4; i++) { float d = xv[i]-m; vs += d*d; }
    float var = block_sum256(vs) * (1.f/D_);
    float rs = rsqrtf(var + EPS_);
    float r[4];
    #pragma unroll
    for (int i = 0; i < 4; i++) {
        int d = tid + 256*i;
        r[i] = (xv[i]-m)*rs*gp[d] + bp[d];
        res[bt*D_ + d] = r[i];
    }
    m = block_sum256(r[0]+r[1]+r[2]+r[3]) * (1.f/D_);
    vs = 0.f;
    #pragma unroll
    for (int i = 0; i < 4; i++) { float d = r[i]-m; vs += d*d; }
    var = block_sum256(vs) * (1.f/D_);
    rs = rsqrtf(var + EPS_);
    #pragma unroll
    for (int i = 0; i < 4; i++) {
        int d = tid + 256*i;
        q0[bt*D_ + d] = (r[i]-m)*rs*gq[d] + bq[d];
    }
}

__global__ void ln_k(const float* __restrict__ x,
                     const float* __restrict__ g, const float* __restrict__ b,
                     float* __restrict__ y) {
    int bt = blockIdx.x, tid = threadIdx.x;
    float xv[4];
    #pragma unroll
    for (int i = 0; i < 4; i++) xv[i] = x[bt*D_ + tid + 256*i];
    float m = block_sum256(xv[0]+xv[1]+xv[2]+xv[3]) * (1.f/D_);
    float vs = 0.f;
    #pragma unroll
    for (int i = 0; i < 4; i++) { float d = xv[i]-m; vs += d*d; }
    float var = block_sum256(vs) * (1.f/D_);
    float rs = rsqrtf(var + EPS_);
    #pragma unroll
    for (int i = 0; i < 4; i++) {
        int d = tid + 256*i;
        y[bt*D_ + d] = (xv[i]-m)*rs*g[d] + b[d];
    }
}

// ---------------- elementwise kernels ----------------
__global__ void shift_lerp_k(const float* __restrict__ x, const float* __restrict__ mu,
                             float* __restrict__ dd, unsigned short* __restrict__ z) {
    int i = blockIdx.x*blockDim.x + threadIdx.x;
    int stride = gridDim.x*blockDim.x;
    for (; i < BTD_; i += stride) {
        int d = i & (D_-1);
        int t = (i >> 10) & (T_-1);
        float xv = x[i];
        float pv = (t == 0) ? 0.f : x[i - D_];
        float del = pv - xv;
        dd[i] = del;
        z[i] = cvt_bf16(fmaf(del, mu[d], xv));
    }
}

__global__ void lerp_dd_k(const float* __restrict__ x, const float* __restrict__ dd,
                          const float* __restrict__ mu, unsigned short* __restrict__ z) {
    int i = blockIdx.x*blockDim.x + threadIdx.x;
    int stride = gridDim.x*blockDim.x;
    for (; i < BTD_; i += stride)
        z[i] = cvt_bf16(fmaf(dd[i], mu[i & (D_-1)], x[i]));
}

__global__ void add_k(const float* __restrict__ a, const float* __restrict__ b,
                      float* __restrict__ c) {
    int i = blockIdx.x*blockDim.x + threadIdx.x;
    int stride = gridDim.x*blockDim.x;
    for (; i < BTD_; i += stride) c[i] = a[i] + b[i];
}

__global__ void final_k(const float* __restrict__ res2, const float* __restrict__ rec,
                        const float* __restrict__ vv, float* __restrict__ out) {
    int i = blockIdx.x*blockDim.x + threadIdx.x;
    int stride = gridDim.x*blockDim.x;
    for (; i < BTD_; i += stride) out[i] = fmaf(rec[i], vv[i], res2[i]);
}

__global__ void zmake_k(const float* __restrict__ x, const float* __restrict__ dd,
                        const float* __restrict__ low, const float* __restrict__ w2,
                        const float* __restrict__ xb, unsigned short* __restrict__ z, int n) {
    int bt = blockIdx.x, tid = threadIdx.x;
    __shared__ float lo[R_];
    if (tid < R_) lo[tid] = low[bt*256 + n*R_ + tid];
    __syncthreads();
    #pragma unroll
    for (int q = 0; q < 4; q++) {
        int d = tid + 256*q;
        const float4* w4 = (const float4*)(w2 + (size_t)d*160 + n*R_);
        float acc = xb[n*D_ + d];
        #pragma unroll
        for (int rr = 0; rr < 8; rr++) {
            float4 wv = w4[rr];
            acc = fmaf(lo[rr*4+0], wv.x, acc);
            acc = fmaf(lo[rr*4+1], wv.y, acc);
            acc = fmaf(lo[rr*4+2], wv.z, acc);
            acc = fmaf(lo[rr*4+3], wv.w, acc);
        }
        int idx = bt*D_ + d;
        z[idx] = cvt_bf16(fmaf(dd[idx], acc, x[idx]));
    }
}

// ---------------- weight convert+transpose: src[K,N] f32 -> dst[Np][Kp] bf16 ----------------
__global__ void cw_k(const float* __restrict__ src, unsigned short* __restrict__ dst,
                     int K, int N, int Kp) {
    __shared__ unsigned short t[64][65];
    int n0 = blockIdx.x << 6, k0 = blockIdx.y << 6;
    int tid = threadIdx.x;
    int jn = tid & 63, si = tid >> 6;
    #pragma unroll
    for (int s = 0; s < 16; s++) {
        int kl = si*16 + s;
        int k = k0 + kl, n = n0 + jn;
        float v = (k < K && n < N) ? src[(size_t)k*N + n] : 0.f;
        t[jn][kl] = cvt_bf16(v);
    }
    __syncthreads();
    #pragma unroll
    for (int s = 0; s < 16; s++) {
        int nl = si*16 + s;
        dst[(size_t)(n0 + nl)*Kp + k0 + jn] = t[nl][jn];
    }
}

// ---------------- bf16 MFMA GEMM: C[M,N] = act(A[M,K] @ Bt[N,K]^T + bias) ----------------
// BM=64 BN=128 BK=64, 4 waves. global_load_lds staging, XOR-swizzled 16B slots
// (slot ^= row&7) applied on the pre-swizzled SOURCE address + swizzled ds_read.
// ACT: 0 none, 1 tanh, 2 sigmoid, 3 sqrelu, 4 exp(-exp(x))
template<int ACT, int OBF>
__global__ __launch_bounds__(256) void mgemm_k(
        const unsigned short* __restrict__ A, const unsigned short* __restrict__ Bt,
        float* __restrict__ C, unsigned short* __restrict__ Cb,
        int N, int K, const float* __restrict__ bias) {
    __shared__ __align__(16) unsigned short Al[64*64];
    __shared__ __align__(16) unsigned short Bl[128*64];
    const int tid = threadIdx.x;
    const int w = tid >> 6, l = tid & 63;
    const int wr = w >> 1, wc = w & 1;
    const int row0 = blockIdx.y << 6, col0 = blockIdx.x << 7;
    f32x4 acc[2][4] = {};

    const unsigned short* aptr[2];
    const unsigned short* bptr[4];
    #pragma unroll
    for (int c = 0; c < 2; c++) {
        int off = c*4096 + tid*16;
        int row = off >> 7;
        int kg = ((off >> 4) & 7) ^ (row & 7);
        aptr[c] = A + (size_t)(row0 + row)*K + kg*8;
    }
    #pragma unroll
    for (int c = 0; c < 4; c++) {
        int off = c*4096 + tid*16;
        int row = off >> 7;
        int kg = ((off >> 4) & 7) ^ (row & 7);
        bptr[c] = Bt + (size_t)(col0 + row)*K + kg*8;
    }

    for (int k0 = 0; k0 < K; k0 += 64) {
        __syncthreads();   // all waves done reading LDS of prev iter
        #pragma unroll
        for (int c = 0; c < 2; c++) {
            gload16(aptr[c], &Al[c*2048 + w*512]);
            aptr[c] += 64;
        }
        #pragma unroll
        for (int c = 0; c < 4; c++) {
            gload16(bptr[c], &Bl[c*2048 + w*512]);
            bptr[c] += 64;
        }
        __syncthreads();   // vmcnt(0) drain + barrier -> tile ready

        short8 af[2][2], bfr[4][2];
        #pragma unroll
        for (int m = 0; m < 2; m++)
        #pragma unroll
        for (int kk = 0; kk < 2; kk++) {
            int row = wr*32 + m*16 + (l & 15);
            int kg = kk*4 + (l >> 4);
            af[m][kk] = *(const short8*)&Al[row*64 + ((kg ^ (row & 7)) << 3)];
        }
        #pragma unroll
        for (int n = 0; n < 4; n++)
        #pragma unroll
        for (int kk = 0; kk < 2; kk++) {
            int row = wc*64 + n*16 + (l & 15);
            int kg = kk*4 + (l >> 4);
            bfr[n][kk] = *(const short8*)&Bl[row*64 + ((kg ^ (row & 7)) << 3)];
        }
        #pragma unroll
        for (int kk = 0; kk < 2; kk++)
        #pragma unroll
        for (int m = 0; m < 2; m++)
        #pragma unroll
        for (int n = 0; n < 4; n++)
            asm volatile("v_mfma_f32_16x16x32_bf16 %0, %1, %2, %0"
                         : "+v"(acc[m][n]) : "v"(af[m][kk]), "v"(bfr[n][kk]));
    }
    asm volatile("s_nop 7\n\ts_nop 7\n\ts_nop 7");

    const int erow = row0 + wr*32 + (l >> 4)*4;
    const int ecol = col0 + wc*64 + (l & 15);
    #pragma unroll
    for (int m = 0; m < 2; m++)
    #pragma unroll
    for (int n = 0; n < 4; n++) {
        float bv = (bias != nullptr) ? bias[ecol + n*16] : 0.f;
        #pragma unroll
        for (int q = 0; q < 4; q++) {
            float x = acc[m][n][q] + bv;
            if (ACT == 1) x = tanhf(x);
            else if (ACT == 2) x = 1.f / (1.f + __expf(-x));
            else if (ACT == 3) { x = fmaxf(x, 0.f); x = x * x; }
            else if (ACT == 4) x = __expf(-__expf(x));
            size_t idx = (size_t)(erow + m*16 + q) * N + (ecol + n*16);
            if (OBF) Cb[idx] = cvt_bf16(x);
            else     C[idx] = x;
        }
    }
}

// ---------------- WKV6 linear-attention scan ----------------
// grid = B*H*8 (8 v-columns per block), block = 64: vi=l&7, kg=l>>3 (8 k-groups of 8).
// ew holds the decay exp(-exp(w)) precomputed in the GEMM epilogue.
// Software-pipelined: t+1 loads issued before t's shuffle/FMA chain.
__global__ void wkv6_k(const float* __restrict__ r, const float* __restrict__ k,
                       const float* __restrict__ v, const float* __restrict__ ew,
                       const float* __restrict__ u, float* __restrict__ o) {
    int bid = blockIdx.x;
    int vc = bid & 7;
    int h  = (bid >> 3) & (H_-1);
    int b  = bid >> 7;
    int l  = threadIdx.x;
    int vi = l & 7, kg = l >> 3;
    int vcol = vc*8 + vi;
    float uv = u[h*DK_ + l];
    float S[8];
    #pragma unroll
    for (int i = 0; i < 8; i++) S[i] = 0.f;
    int base = b*T_*D_ + h*DK_;
    int srcbase = kg*8;
    int off = base;
    float rv = r[off+l], kv_ = k[off+l], ev = ew[off+l], vt = v[off+vcol];
    for (int t = 0; t < T_; t++) {
        float rv2 = 0.f, kv2 = 0.f, ev2 = 0.f, vt2 = 0.f;
        if (t < T_-1) {
            int o2 = off + D_;
            rv2 = r[o2+l]; kv2 = k[o2+l]; ev2 = ew[o2+l]; vt2 = v[o2+vcol];
        }
        float rav = rv * uv * kv_;
        #pragma unroll
        for (int ofs = 32; ofs > 0; ofs >>= 1) rav += __shfl_xor(rav, ofs);
        float oacc = 0.f;
        #pragma unroll
        for (int i = 0; i < 8; i++) {
            float ri = __shfl(rv,  srcbase + i);
            float ki = __shfl(kv_, srcbase + i);
            float ei = __shfl(ev,  srcbase + i);
            oacc = fmaf(ri, S[i], oacc);
            S[i] = fmaf(ei, S[i], ki * vt);
        }
        oacc += __shfl_xor(oacc, 8);
        oacc += __shfl_xor(oacc, 16);
        oacc += __shfl_xor(oacc, 32);
        if (kg == 0) o[off + vcol] = fmaf(rav, vt, oacc);
        off += D_;
        rv = rv2; kv_ = kv2; ev = ev2; vt = vt2;
    }
}

// ---------------- per-head GroupNorm * swish(gate), bf16 out ----------------
__global__ void gn_gate_k(const float* __restrict__ o, const float* __restrict__ g,
                          const float* __restrict__ gng, const float* __restrict__ gnb,
                          unsigned short* __restrict__ out) {
    int bid = blockIdx.x;
    int h = bid & (H_-1);
    int bt = bid >> 4;
    int l = threadIdx.x;
    int idx = bt*D_ + h*DV_ + l;
    float x = o[idx];
    float s = x;
    #pragma unroll
    for (int ofs = 32; ofs > 0; ofs >>= 1) s += __shfl_xor(s, ofs);
    float m = s * (1.f/DV_);
    float dv = x - m;
    float v2 = dv*dv;
    #pragma unroll
    for (int ofs = 32; ofs > 0; ofs >>= 1) v2 += __shfl_xor(v2, ofs);
    float var = v2 * (1.f/DV_);
    float xn = dv * rsqrtf(var + EPS_);
    int d = h*DV_ + l;
    float gg = g[idx];
    float sw = gg / (1.f + __expf(-gg));
    out[idx] = cvt_bf16((xn * gng[d] + gnb[d]) * sw);
}

// ---------------- host ----------------
extern "C" void kernel_launch(void* const* d_in, const int* in_sizes, int n_in,
                              void* d_out, int out_size, void* d_ws, size_t ws_size,
                              hipStream_t stream) {
    const float* const* in = (const float* const*)d_in;
    const float* query  = in[0];
    const float* keyval = in[1];
    const float* lnp_g = in[2]; const float* lnp_b = in[3];
    const float* lnq_g = in[4]; const float* lnq_b = in[5];
    const float* lnkv_g = in[6]; const float* lnkv_b = in[7];
    const float* lnf_g = in[8]; const float* lnf_b = in[9];
    float* out = (float*)d_out;

    float* p = (float*)d_ws;
    float* res = p;  p += BTD_;
    float* xa  = p;  p += BTD_;
    float* xb  = p;  p += BTD_;
    float* dd  = p;  p += BTD_;
    float* rbf = p;  p += BTD_;
    float* kbf = p;  p += BTD_;
    float* vbf = p;  p += BTD_;
    float* gbf = p;  p += BTD_;
    float* wbf = p;  p += BTD_;
    float* obf = p;  p += BTD_;
    float* lowb = p; p += BT_*256;
    unsigned short* zb   = (unsigned short*)p;
    unsigned short* wlb  = zb + BTD_;
    unsigned short* wscr = wlb + BT_*128;
    unsigned short* kkbb = (unsigned short*)rbf;   // [BT,3584] bf16 over rbf+kbf (FFN only)

    auto cw = [&](const float* src, int K, int N, int Kp, int Np) {
        cw_k<<<dim3(Np >> 6, Kp >> 6), 256, 0, stream>>>(src, wscr, K, N, Kp);
    };
    auto mg = [&](const unsigned short* A, float* Cf, unsigned short* Cbf,
                  int N, int K, int act, const float* bias) {
        dim3 g(N >> 7, BT_ >> 6);
        if (act == 0)          mgemm_k<0,0><<<g,256,0,stream>>>(A, wscr, Cf, nullptr, N, K, bias);
        else if (act == 1 && !Cbf) mgemm_k<1,0><<<g,256,0,stream>>>(A, wscr, Cf, nullptr, N, K, bias);
        else if (act == 1)     mgemm_k<1,1><<<g,256,0,stream>>>(A, wscr, nullptr, Cbf, N, K, bias);
        else if (act == 2)     mgemm_k<2,0><<<g,256,0,stream>>>(A, wscr, Cf, nullptr, N, K, bias);
        else if (act == 3)     mgemm_k<3,1><<<g,256,0,stream>>>(A, wscr, nullptr, Cbf, N, K, bias);
        else                   mgemm_k<4,0><<<g,256,0,stream>>>(A, wscr, Cf, nullptr, N, K, bias);
    };

    ln2_k<<<BT_, 256, 0, stream>>>(query, lnp_g, lnp_b, lnq_g, lnq_b, res, xa);

    auto run_attn = [&](const float* xq, const float* xkv, bool self, int pb, float* outbuf) {
        const float* x_mu  = in[pb+0];  const float* x_w1  = in[pb+1];
        const float* x_w2  = in[pb+2];  const float* x_bias= in[pb+3];
        const float* r_w   = in[pb+4];  const float* k_w   = in[pb+5];
        const float* v_w   = in[pb+6];  const float* g_w   = in[pb+7];
        const float* w_a   = in[pb+8];  const float* w_b   = in[pb+9];
        const float* w_bias= in[pb+10]; const float* u     = in[pb+11];
        const float* gn_g  = in[pb+12]; const float* gn_b  = in[pb+13];
        const float* o_w   = in[pb+14];

        shift_lerp_k<<<1024, 256, 0, stream>>>(xq, x_mu, dd, zb);
        cw(x_w1, 1024, 160, 1024, 256);
        mg(zb, lowb, nullptr, 256, 1024, 1, nullptr);
        zmake_k<<<BT_, 256, 0, stream>>>(xq, dd, lowb, x_w2, x_bias, zb, 0);
        cw(r_w, 1024, 1024, 1024, 1024);
        mg(zb, rbf, nullptr, 1024, 1024, 0, nullptr);
        zmake_k<<<BT_, 256, 0, stream>>>(xq, dd, lowb, x_w2, x_bias, zb, 4);
        cw(g_w, 1024, 1024, 1024, 1024);
        mg(zb, gbf, nullptr, 1024, 1024, 0, nullptr);

        const float* xs = xq;
        if (!self) {
            shift_lerp_k<<<1024, 256, 0, stream>>>(xkv, x_mu, dd, zb);
            cw(x_w1, 1024, 160, 1024, 256);
            mg(zb, lowb, nullptr, 256, 1024, 1, nullptr);
            xs = xkv;
        }
        zmake_k<<<BT_, 256, 0, stream>>>(xs, dd, lowb, x_w2, x_bias, zb, 1);
        cw(w_a, 1024, 64, 1024, 128);
        mg(zb, nullptr, wlb, 128, 1024, 1, nullptr);            // tanh, bf16 out
        cw(w_b, 64, 1024, 128, 1024);
        mg(wlb, wbf, nullptr, 1024, 128, 4, w_bias);            // ev = exp(-exp(.))
        zmake_k<<<BT_, 256, 0, stream>>>(xs, dd, lowb, x_w2, x_bias, zb, 2);
        cw(k_w, 1024, 1024, 1024, 1024);
        mg(zb, kbf, nullptr, 1024, 1024, 0, nullptr);
        zmake_k<<<BT_, 256, 0, stream>>>(xs, dd, lowb, x_w2, x_bias, zb, 3);
        cw(v_w, 1024, 1024, 1024, 1024);
        mg(zb, vbf, nullptr, 1024, 1024, 0, nullptr);

        wkv6_k<<<B_*H_*8, 64, 0, stream>>>(rbf, kbf, vbf, wbf, u, obf);
        gn_gate_k<<<BT_*H_, 64, 0, stream>>>(obf, gbf, gn_g, gn_b, zb);
        cw(o_w, 1024, 1024, 1024, 1024);
        mg(zb, outbuf, nullptr, 1024, 1024, 0, nullptr);
    };

    run_attn(xa, xa, true, 10, xb);                      // self: xa -> xb
    ln_k<<<BT_, 256, 0, stream>>>(keyval, lnkv_g, lnkv_b, xa);   // kv0 -> xa
    run_attn(xb, xa, false, 25, xa);                     // cross: -> xa (written last)

    add_k<<<1024, 256, 0, stream>>>(xa, res, xb);        // res2 -> xb
    ln_k<<<BT_, 256, 0, stream>>>(xb, lnf_g, lnf_b, res);// ffn input -> res

    shift_lerp_k<<<1024, 256, 0, stream>>>(res, in[40], dd, zb);
    cw(in[41], 1024, 3584, 1024, 3584);
    mg(zb, nullptr, kkbb, 3584, 1024, 3, nullptr);       // sqrelu key, bf16
    cw(in[42], 3584, 1024, 3584, 1024);
    mg(kkbb, obf, nullptr, 1024, 3584, 0, nullptr);      // value
    lerp_dd_k<<<1024, 256, 0, stream>>>(res, dd, in[43], zb);
    cw(in[44], 1024, 1024, 1024, 1024);
    mg(zb, vbf, nullptr, 1024, 1024, 2, nullptr);        // sigmoid rec -> vbf
    final_k<<<1024, 256, 0, stream>>>(xb, vbf, obf, out);
}

// Round 5
// 1024.919 us; speedup vs baseline: 4.9466x; 1.8556x over previous
//
#include <hip/hip_runtime.h>
#include <math.h>

#define B_ 4
#define T_ 512
#define D_ 1024
#define H_ 16
#define DK_ 64
#define DV_ 64
#define R_ 32
#define GLR_ 64
#define INTER_ 3584
#define BT_ (B_*T_)
#define BTD_ (BT_*D_)
#define EPS_ 1e-5f
#define NC_ 8      // wkv chunks
#define CL_ 64     // chunk length (T_/NC_)

typedef short short8 __attribute__((ext_vector_type(8)));
typedef float f32x4 __attribute__((ext_vector_type(4)));

__device__ __forceinline__ unsigned short cvt_bf16(float f) {
    unsigned u = __float_as_uint(f);
    return (unsigned short)((u + 0x7FFFu + ((u >> 16) & 1u)) >> 16);
}

// async global->LDS, 16B per lane (dest = wave-uniform base + lane*16)
__device__ __forceinline__ void gload16(const unsigned short* g, unsigned short* l) {
    __builtin_amdgcn_global_load_lds(
        (const __attribute__((address_space(1))) void*)g,
        (__attribute__((address_space(3))) void*)l, 16, 0, 0);
}

// ---------------- block reduction helper (256 threads) ----------------
__device__ __forceinline__ float block_sum256(float v) {
    __shared__ float red[4];
    #pragma unroll
    for (int o = 32; o > 0; o >>= 1) v += __shfl_down(v, o);
    __syncthreads();
    if ((threadIdx.x & 63) == 0) red[threadIdx.x >> 6] = v;
    __syncthreads();
    return red[0] + red[1] + red[2] + red[3];
}

// ---------------- LayerNorm kernels ----------------
__global__ void ln2_k(const float* __restrict__ x,
                      const float* __restrict__ gp, const float* __restrict__ bp,
                      const float* __restrict__ gq, const float* __restrict__ bq,
                      float* __restrict__ res, float* __restrict__ q0) {
    int bt = blockIdx.x, tid = threadIdx.x;
    float xv[4];
    #pragma unroll
    for (int i = 0; i < 4; i++) xv[i] = x[bt*D_ + tid + 256*i];
    float m = block_sum256(xv[0]+xv[1]+xv[2]+xv[3]) * (1.f/D_);
    float vs = 0.f;
    #pragma unroll
    for (int i = 0; i < 4; i++) { float d = xv[i]-m; vs += d*d; }
    float var = block_sum256(vs) * (1.f/D_);
    float rs = rsqrtf(var + EPS_);
    float r[4];
    #pragma unroll
    for (int i = 0; i < 4; i++) {
        int d = tid + 256*i;
        r[i] = (xv[i]-m)*rs*gp[d] + bp[d];
        res[bt*D_ + d] = r[i];
    }
    m = block_sum256(r[0]+r[1]+r[2]+r[3]) * (1.f/D_);
    vs = 0.f;
    #pragma unroll
    for (int i = 0; i < 4; i++) { float d = r[i]-m; vs += d*d; }
    var = block_sum256(vs) * (1.f/D_);
    rs = rsqrtf(var + EPS_);
    #pragma unroll
    for (int i = 0; i < 4; i++) {
        int d = tid + 256*i;
        q0[bt*D_ + d] = (r[i]-m)*rs*gq[d] + bq[d];
    }
}

__global__ void ln_k(const float* __restrict__ x,
                     const float* __restrict__ g, const float* __restrict__ b,
                     float* __restrict__ y) {
    int bt = blockIdx.x, tid = threadIdx.x;
    float xv[4];
    #pragma unroll
    for (int i = 0; i < 4; i++) xv[i] = x[bt*D_ + tid + 256*i];
    float m = block_sum256(xv[0]+xv[1]+xv[2]+xv[3]) * (1.f/D_);
    float vs = 0.f;
    #pragma unroll
    for (int i = 0; i < 4; i++) { float d = xv[i]-m; vs += d*d; }
    float var = block_sum256(vs) * (1.f/D_);
    float rs = rsqrtf(var + EPS_);
    #pragma unroll
    for (int i = 0; i < 4; i++) {
        int d = tid + 256*i;
        y[bt*D_ + d] = (xv[i]-m)*rs*g[d] + b[d];
    }
}

// ---------------- elementwise kernels ----------------
__global__ void shift_lerp_k(const float* __restrict__ x, const float* __restrict__ mu,
                             float* __restrict__ dd, unsigned short* __restrict__ z) {
    int i = blockIdx.x*blockDim.x + threadIdx.x;
    int stride = gridDim.x*blockDim.x;
    for (; i < BTD_; i += stride) {
        int d = i & (D_-1);
        int t = (i >> 10) & (T_-1);
        float xv = x[i];
        float pv = (t == 0) ? 0.f : x[i - D_];
        float del = pv - xv;
        dd[i] = del;
        z[i] = cvt_bf16(fmaf(del, mu[d], xv));
    }
}

__global__ void lerp_dd_k(const float* __restrict__ x, const float* __restrict__ dd,
                          const float* __restrict__ mu, unsigned short* __restrict__ z) {
    int i = blockIdx.x*blockDim.x + threadIdx.x;
    int stride = gridDim.x*blockDim.x;
    for (; i < BTD_; i += stride)
        z[i] = cvt_bf16(fmaf(dd[i], mu[i & (D_-1)], x[i]));
}

__global__ void add_k(const float* __restrict__ a, const float* __restrict__ b,
                      float* __restrict__ c) {
    int i = blockIdx.x*blockDim.x + threadIdx.x;
    int stride = gridDim.x*blockDim.x;
    for (; i < BTD_; i += stride) c[i] = a[i] + b[i];
}

__global__ void final_k(const float* __restrict__ res2, const float* __restrict__ rec,
                        const float* __restrict__ vv, float* __restrict__ out) {
    int i = blockIdx.x*blockDim.x + threadIdx.x;
    int stride = gridDim.x*blockDim.x;
    for (; i < BTD_; i += stride) out[i] = fmaf(rec[i], vv[i], res2[i]);
}

// w2[D][5][R] f32 -> dst[n][D][64] bf16 (rows 32..63 zero)
__global__ void cvtw2_k(const float* __restrict__ w2, unsigned short* __restrict__ dst) {
    int idx = blockIdx.x*256 + threadIdx.x;     // 5*1024*64 = 327680
    if (idx >= 5*1024*64) return;
    int kk = idx & 63;
    int d = (idx >> 6) & 1023;
    int n = idx >> 16;
    float v = (kk < 32) ? w2[d*160 + n*32 + kk] : 0.f;
    dst[idx] = cvt_bf16(v);
}

// ---------------- weight convert+transpose: src[K,N] f32 -> dst[Np][Kp] bf16 ----------------
__global__ void cw_k(const float* __restrict__ src, unsigned short* __restrict__ dst,
                     int K, int N, int Kp) {
    __shared__ unsigned short t[64][65];
    int n0 = blockIdx.x << 6, k0 = blockIdx.y << 6;
    int tid = threadIdx.x;
    int jn = tid & 63, si = tid >> 6;
    #pragma unroll
    for (int s = 0; s < 16; s++) {
        int kl = si*16 + s;
        int k = k0 + kl, n = n0 + jn;
        float v = (k < K && n < N) ? src[(size_t)k*N + n] : 0.f;
        t[jn][kl] = cvt_bf16(v);
    }
    __syncthreads();
    #pragma unroll
    for (int s = 0; s < 16; s++) {
        int nl = si*16 + s;
        dst[(size_t)(n0 + nl)*Kp + k0 + jn] = t[nl][jn];
    }
}

// ---------------- bf16 MFMA GEMM: C[M,N] = act(A[M,K] @ Bt[N,K]^T + bias) ----------------
// BM=64 BN=64 BK=64, 4 waves (2x2), per-wave 32x32, acc 2x2 frags.
// global_load_lds staging; XOR-swizzled 16B slots (slot ^= row&7) via pre-swizzled source.
// ACT: 0 none, 1 tanh, 2 sigmoid, 3 sqrelu, 4 exp(-exp(x)), 5 z-combine x+dd*(acc+bias)
template<int ACT, int OBF>
__global__ __launch_bounds__(256) void mgemm_k(
        const unsigned short* __restrict__ A, const unsigned short* __restrict__ Bt,
        float* __restrict__ C, unsigned short* __restrict__ Cb,
        int N, int K, int lda, const float* __restrict__ bias,
        const float* __restrict__ xin, const float* __restrict__ ddin) {
    __shared__ __align__(16) unsigned short Al[64*64];
    __shared__ __align__(16) unsigned short Bl[64*64];
    const int tid = threadIdx.x;
    const int w = tid >> 6, l = tid & 63;
    const int wr = w >> 1, wc = w & 1;
    const int row0 = blockIdx.y << 6, col0 = blockIdx.x << 6;
    f32x4 acc[2][2] = {};

    const unsigned short* aptr[2];
    const unsigned short* bptr[2];
    #pragma unroll
    for (int c = 0; c < 2; c++) {
        int off = c*4096 + tid*16;
        int row = off >> 7;
        int kg = ((off >> 4) & 7) ^ (row & 7);
        aptr[c] = A + (size_t)(row0 + row)*lda + kg*8;
        bptr[c] = Bt + (size_t)(col0 + row)*K + kg*8;
    }

    for (int k0 = 0; k0 < K; k0 += 64) {
        __syncthreads();   // all waves done reading LDS of prev iter
        #pragma unroll
        for (int c = 0; c < 2; c++) {
            gload16(aptr[c], &Al[c*2048 + w*512]);
            aptr[c] += 64;
        }
        #pragma unroll
        for (int c = 0; c < 2; c++) {
            gload16(bptr[c], &Bl[c*2048 + w*512]);
            bptr[c] += 64;
        }
        __syncthreads();   // vmcnt(0) drain + barrier -> tile ready

        short8 af[2][2], bfr[2][2];
        #pragma unroll
        for (int m = 0; m < 2; m++)
        #pragma unroll
        for (int kk = 0; kk < 2; kk++) {
            int row = wr*32 + m*16 + (l & 15);
            int kg = kk*4 + (l >> 4);
            af[m][kk] = *(const short8*)&Al[row*64 + ((kg ^ (row & 7)) << 3)];
        }
        #pragma unroll
        for (int n = 0; n < 2; n++)
        #pragma unroll
        for (int kk = 0; kk < 2; kk++) {
            int row = wc*32 + n*16 + (l & 15);
            int kg = kk*4 + (l >> 4);
            bfr[n][kk] = *(const short8*)&Bl[row*64 + ((kg ^ (row & 7)) << 3)];
        }
        #pragma unroll
        for (int kk = 0; kk < 2; kk++)
        #pragma unroll
        for (int m = 0; m < 2; m++)
        #pragma unroll
        for (int n = 0; n < 2; n++)
            asm volatile("v_mfma_f32_16x16x32_bf16 %0, %1, %2, %0"
                         : "+v"(acc[m][n]) : "v"(af[m][kk]), "v"(bfr[n][kk]));
    }
    asm volatile("s_nop 7\n\ts_nop 7\n\ts_nop 7");

    const int erow = row0 + wr*32 + (l >> 4)*4;
    const int ecol = col0 + wc*32 + (l & 15);
    #pragma unroll
    for (int m = 0; m < 2; m++)
    #pragma unroll
    for (int n = 0; n < 2; n++) {
        float bv = (bias != nullptr) ? bias[ecol + n*16] : 0.f;
        #pragma unroll
        for (int q = 0; q < 4; q++) {
            float x = acc[m][n][q] + bv;
            size_t idx = (size_t)(erow + m*16 + q) * N + (ecol + n*16);
            if (ACT == 1) x = tanhf(x);
            else if (ACT == 2) x = 1.f / (1.f + __expf(-x));
            else if (ACT == 3) { x = fmaxf(x, 0.f); x = x * x; }
            else if (ACT == 4) x = __expf(-__expf(x));
            else if (ACT == 5) x = fmaf(ddin[idx], x, xin[idx]);
            if (OBF) Cb[idx] = cvt_bf16(x);
            else     C[idx] = x;
        }
    }
}

// ---------------- chunked WKV6 ----------------
// lane layout: vi = l&7 (8 v-cols), kg = l>>3 (8 k-groups of 8); vcol = vc*8+vi.
// bid = ((b*H + h)*NC + c)*8 + vc  for A/B kernels.

// Phase A: per-chunk local state from zero + per-chunk decay product.
__global__ void wkvA_k(const float* __restrict__ k, const float* __restrict__ v,
                       const float* __restrict__ ew, float* __restrict__ Bws,
                       float* __restrict__ Aws) {
    int bid = blockIdx.x;
    int vc = bid & 7;
    int c  = (bid >> 3) & (NC_-1);
    int h  = (bid >> 6) & (H_-1);
    int b  = bid >> 10;
    int l = threadIdx.x;
    int vi = l & 7, kg = l >> 3, sb = kg*8;
    int vcol = vc*8 + vi;
    int bh = b*H_ + h;
    float S[8];
    #pragma unroll
    for (int i = 0; i < 8; i++) S[i] = 0.f;
    float pe = 1.f;
    int off = (b*T_ + c*CL_)*D_ + h*DK_;
    float4 kA = *(const float4*)&k[off+sb],  kB = *(const float4*)&k[off+sb+4];
    float4 eA = *(const float4*)&ew[off+sb], eB = *(const float4*)&ew[off+sb+4];
    float vt = v[off+vcol];
    float eOwn = (vc == 0) ? ew[off+l] : 1.f;
    for (int s = 0; s < CL_; s++) {
        float4 kA2 = kA, kB2 = kB, eA2 = eA, eB2 = eB;
        float vt2 = vt, eOwn2 = eOwn;
        if (s < CL_-1) {
            int o2 = off + D_;
            kA2 = *(const float4*)&k[o2+sb];  kB2 = *(const float4*)&k[o2+sb+4];
            eA2 = *(const float4*)&ew[o2+sb]; eB2 = *(const float4*)&ew[o2+sb+4];
            vt2 = v[o2+vcol];
            if (vc == 0) eOwn2 = ew[o2+l];
        }
        float kk[8] = {kA.x,kA.y,kA.z,kA.w,kB.x,kB.y,kB.z,kB.w};
        float ee[8] = {eA.x,eA.y,eA.z,eA.w,eB.x,eB.y,eB.z,eB.w};
        #pragma unroll
        for (int i = 0; i < 8; i++)
            S[i] = fmaf(ee[i], S[i], kk[i]*vt);
        pe *= eOwn;
        off += D_;
        kA = kA2; kB = kB2; eA = eA2; eB = eB2; vt = vt2; eOwn = eOwn2;
    }
    size_t bbase = ((size_t)(bh*NC_ + c))*4096;
    #pragma unroll
    for (int i = 0; i < 8; i++) Bws[bbase + (sb+i)*64 + vcol] = S[i];
    if (vc == 0) Aws[(bh*NC_ + c)*64 + l] = pe;
}

// Prefix: checkpoint states at chunk starts. bid = bh*8 + vc.
__global__ void wkvP_k(const float* __restrict__ Aws, const float* __restrict__ Bws,
                       float* __restrict__ CS) {
    int bid = blockIdx.x;
    int vc = bid & 7;
    int bh = bid >> 3;
    int l = threadIdx.x;
    int vi = l & 7, kg = l >> 3, sb = kg*8;
    int vcol = vc*8 + vi;
    float S[8];
    #pragma unroll
    for (int i = 0; i < 8; i++) S[i] = 0.f;
    for (int c = 0; c < NC_; c++) {
        size_t base = ((size_t)(bh*NC_ + c))*4096;
        #pragma unroll
        for (int i = 0; i < 8; i++) CS[base + (sb+i)*64 + vcol] = S[i];
        #pragma unroll
        for (int i = 0; i < 8; i++) {
            float a  = Aws[(bh*NC_ + c)*64 + sb + i];
            float bb = Bws[base + (sb+i)*64 + vcol];
            S[i] = fmaf(a, S[i], bb);
        }
    }
}

// Phase B: replay chunk from checkpoint, emitting outputs.
__global__ void wkvB_k(const float* __restrict__ r, const float* __restrict__ k,
                       const float* __restrict__ v, const float* __restrict__ ew,
                       const float* __restrict__ u, const float* __restrict__ CS,
                       float* __restrict__ o) {
    int bid = blockIdx.x;
    int vc = bid & 7;
    int c  = (bid >> 3) & (NC_-1);
    int h  = (bid >> 6) & (H_-1);
    int b  = bid >> 10;
    int l = threadIdx.x;
    int vi = l & 7, kg = l >> 3, sb = kg*8;
    int vcol = vc*8 + vi;
    int bh = b*H_ + h;
    float S[8], u8[8];
    size_t cbase = ((size_t)(bh*NC_ + c))*4096;
    #pragma unroll
    for (int i = 0; i < 8; i++) S[i] = CS[cbase + (sb+i)*64 + vcol];
    #pragma unroll
    for (int i = 0; i < 8; i++) u8[i] = u[h*DK_ + sb + i];
    int off = (b*T_ + c*CL_)*D_ + h*DK_;
    float4 rA = *(const float4*)&r[off+sb],  rB = *(const float4*)&r[off+sb+4];
    float4 kA = *(const float4*)&k[off+sb],  kB = *(const float4*)&k[off+sb+4];
    float4 eA = *(const float4*)&ew[off+sb], eB = *(const float4*)&ew[off+sb+4];
    float vt = v[off+vcol];
    for (int s = 0; s < CL_; s++) {
        float4 rA2 = rA, rB2 = rB, kA2 = kA, kB2 = kB, eA2 = eA, eB2 = eB;
        float vt2 = vt;
        if (s < CL_-1) {
            int o2 = off + D_;
            rA2 = *(const float4*)&r[o2+sb];  rB2 = *(const float4*)&r[o2+sb+4];
            kA2 = *(const float4*)&k[o2+sb];  kB2 = *(const float4*)&k[o2+sb+4];
            eA2 = *(const float4*)&ew[o2+sb]; eB2 = *(const float4*)&ew[o2+sb+4];
            vt2 = v[o2+vcol];
        }
        float rr[8] = {rA.x,rA.y,rA.z,rA.w,rB.x,rB.y,rB.z,rB.w};
        float kk[8] = {kA.x,kA.y,kA.z,kA.w,kB.x,kB.y,kB.z,kB.w};
        float ee[8] = {eA.x,eA.y,eA.z,eA.w,eB.x,eB.y,eB.z,eB.w};
        float oacc = 0.f;
        #pragma unroll
        for (int i = 0; i < 8; i++) {
            float kv = kk[i]*vt;
            oacc = fmaf(rr[i], fmaf(u8[i], kv, S[i]), oacc);
            S[i] = fmaf(ee[i], S[i], kv);
        }
        oacc += __shfl_xor(oacc, 8);
        oacc += __shfl_xor(oacc, 16);
        oacc += __shfl_xor(oacc, 32);
        if (kg == 0) o[off + vcol] = oacc;
        off += D_;
        rA = rA2; rB = rB2; kA = kA2; kB = kB2; eA = eA2; eB = eB2; vt = vt2;
    }
}

// ---------------- per-head GroupNorm * swish(gate), bf16 out ----------------
__global__ void gn_gate_k(const float* __restrict__ o, const float* __restrict__ g,
                          const float* __restrict__ gng, const float* __restrict__ gnb,
                          unsigned short* __restrict__ out) {
    int bid = blockIdx.x;
    int h = bid & (H_-1);
    int bt = bid >> 4;
    int l = threadIdx.x;
    int idx = bt*D_ + h*DV_ + l;
    float x = o[idx];
    float s = x;
    #pragma unroll
    for (int ofs = 32; ofs > 0; ofs >>= 1) s += __shfl_xor(s, ofs);
    float m = s * (1.f/DV_);
    float dv = x - m;
    float v2 = dv*dv;
    #pragma unroll
    for (int ofs = 32; ofs > 0; ofs >>= 1) v2 += __shfl_xor(v2, ofs);
    float var = v2 * (1.f/DV_);
    float xn = dv * rsqrtf(var + EPS_);
    int d = h*DV_ + l;
    float gg = g[idx];
    float sw = gg / (1.f + __expf(-gg));
    out[idx] = cvt_bf16((xn * gng[d] + gnb[d]) * sw);
}

// ---------------- host ----------------
extern "C" void kernel_launch(void* const* d_in, const int* in_sizes, int n_in,
                              void* d_out, int out_size, void* d_ws, size_t ws_size,
                              hipStream_t stream) {
    const float* const* in = (const float* const*)d_in;
    const float* query  = in[0];
    const float* keyval = in[1];
    const float* lnp_g = in[2]; const float* lnp_b = in[3];
    const float* lnq_g = in[4]; const float* lnq_b = in[5];
    const float* lnkv_g = in[6]; const float* lnkv_b = in[7];
    const float* lnf_g = in[8]; const float* lnf_b = in[9];
    float* out = (float*)d_out;

    // workspace carve (~95 MB)
    float* p = (float*)d_ws;
    float* res = p;  p += BTD_;
    float* xa  = p;  p += BTD_;
    float* xb  = p;  p += BTD_;
    float* dd  = p;  p += BTD_;   // also aliased as wkv Bws during scan
    float* rbf = p;  p += BTD_;
    float* kbf = p;  p += BTD_;
    float* vbf = p;  p += BTD_;
    float* gbf = p;  p += BTD_;
    float* wbf = p;  p += BTD_;
    float* obf = p;  p += BTD_;
    float* Aws = p;  p += 64*NC_*64;
    unsigned short* zb     = (unsigned short*)p;
    unsigned short* lowbq  = zb + BTD_;
    unsigned short* lowbkv = lowbq + BT_*256;
    unsigned short* wlb    = lowbkv + BT_*256;
    unsigned short* w1b    = wlb + BT_*128;
    unsigned short* w2b    = w1b + 256*1024;
    unsigned short* wscr   = w2b + 5*1024*64;
    unsigned short* kkbb = (unsigned short*)rbf;   // [BT,3584] bf16 over rbf+kbf (FFN only)

    auto cw = [&](const float* src, unsigned short* dst, int K, int N, int Kp, int Np) {
        cw_k<<<dim3(Np >> 6, Kp >> 6), 256, 0, stream>>>(src, dst, K, N, Kp);
    };
    auto mg = [&](const unsigned short* A, const unsigned short* W,
                  float* Cf, unsigned short* Cbf, int N, int K, int lda, int act,
                  const float* bias, const float* xin, const float* ddin) {
        dim3 g(N >> 6, BT_ >> 6);
        if (act == 0)      mgemm_k<0,0><<<g,256,0,stream>>>(A, W, Cf, nullptr, N, K, lda, bias, nullptr, nullptr);
        else if (act == 1) mgemm_k<1,1><<<g,256,0,stream>>>(A, W, nullptr, Cbf, N, K, lda, bias, nullptr, nullptr);
        else if (act == 2) mgemm_k<2,0><<<g,256,0,stream>>>(A, W, Cf, nullptr, N, K, lda, bias, nullptr, nullptr);
        else if (act == 3) mgemm_k<3,1><<<g,256,0,stream>>>(A, W, nullptr, Cbf, N, K, lda, bias, nullptr, nullptr);
        else if (act == 4) mgemm_k<4,0><<<g,256,0,stream>>>(A, W, Cf, nullptr, N, K, lda, bias, nullptr, nullptr);
        else               mgemm_k<5,1><<<g,256,0,stream>>>(A, W, nullptr, Cbf, N, K, lda, bias, xin, ddin);
    };

    ln2_k<<<BT_, 256, 0, stream>>>(query, lnp_g, lnp_b, lnq_g, lnq_b, res, xa);

    auto run_attn = [&](const float* xq, const float* xkv, bool self, int pb,
                        float* outbuf, float* csbuf) {
        const float* x_mu  = in[pb+0];  const float* x_w1  = in[pb+1];
        const float* x_w2  = in[pb+2];  const float* x_bias= in[pb+3];
        const float* r_w   = in[pb+4];  const float* k_w   = in[pb+5];
        const float* v_w   = in[pb+6];  const float* g_w   = in[pb+7];
        const float* w_a   = in[pb+8];  const float* w_b   = in[pb+9];
        const float* w_bias= in[pb+10]; const float* u     = in[pb+11];
        const float* gn_g  = in[pb+12]; const float* gn_b  = in[pb+13];
        const float* o_w   = in[pb+14];

        // q-side: lowb_q, then z0 -> r, z4 -> g
        shift_lerp_k<<<1024, 256, 0, stream>>>(xq, x_mu, dd, zb);
        cw(x_w1, w1b, 1024, 160, 1024, 256);
        cvtw2_k<<<1280, 256, 0, stream>>>(x_w2, w2b);
        mg(zb, w1b, nullptr, lowbq, 256, 1024, 1024, 1, nullptr, nullptr, nullptr);
        mg(lowbq + 0*32, w2b + 0*65536, nullptr, zb, 1024, 64, 256, 5, x_bias + 0*D_, xq, dd);
        cw(r_w, wscr, 1024, 1024, 1024, 1024);
        mg(zb, wscr, rbf, nullptr, 1024, 1024, 1024, 0, nullptr, nullptr, nullptr);
        mg(lowbq + 4*32, w2b + 4*65536, nullptr, zb, 1024, 64, 256, 5, x_bias + 4*D_, xq, dd);
        cw(g_w, wscr, 1024, 1024, 1024, 1024);
        mg(zb, wscr, gbf, nullptr, 1024, 1024, 1024, 0, nullptr, nullptr, nullptr);

        // kv-side: lowb_kv (cross recomputes dd from xkv)
        const float* xs = xq;
        const unsigned short* lb = lowbq;
        if (!self) {
            shift_lerp_k<<<1024, 256, 0, stream>>>(xkv, x_mu, dd, zb);
            mg(zb, w1b, nullptr, lowbkv, 256, 1024, 1024, 1, nullptr, nullptr, nullptr);
            xs = xkv;
            lb = lowbkv;
        }
        mg(lb + 1*32, w2b + 1*65536, nullptr, zb, 1024, 64, 256, 5, x_bias + 1*D_, xs, dd);
        cw(w_a, wscr, 1024, 64, 1024, 128);
        mg(zb, wscr, nullptr, wlb, 128, 1024, 1024, 1, nullptr, nullptr, nullptr);
        cw(w_b, wscr, 64, 1024, 128, 1024);
        mg(wlb, wscr, wbf, nullptr, 1024, 128, 128, 4, w_bias, nullptr, nullptr);
        mg(lb + 2*32, w2b + 2*65536, nullptr, zb, 1024, 64, 256, 5, x_bias + 2*D_, xs, dd);
        cw(k_w, wscr, 1024, 1024, 1024, 1024);
        mg(zb, wscr, kbf, nullptr, 1024, 1024, 1024, 0, nullptr, nullptr, nullptr);
        mg(lb + 3*32, w2b + 3*65536, nullptr, zb, 1024, 64, 256, 5, x_bias + 3*D_, xs, dd);
        cw(v_w, wscr, 1024, 1024, 1024, 1024);
        mg(zb, wscr, vbf, nullptr, 1024, 1024, 1024, 0, nullptr, nullptr, nullptr);

        // chunked scan: A (local states) -> P (prefix checkpoints) -> B (replay)
        wkvA_k<<<B_*H_*NC_*8, 64, 0, stream>>>(kbf, vbf, wbf, dd, Aws);
        wkvP_k<<<64*8, 64, 0, stream>>>(Aws, dd, csbuf);
        wkvB_k<<<B_*H_*NC_*8, 64, 0, stream>>>(rbf, kbf, vbf, wbf, u, csbuf, obf);

        gn_gate_k<<<BT_*H_, 64, 0, stream>>>(obf, gbf, gn_g, gn_b, zb);
        cw(o_w, wscr, 1024, 1024, 1024, 1024);
        mg(zb, wscr, outbuf, nullptr, 1024, 1024, 1024, 0, nullptr, nullptr, nullptr);
    };

    run_attn(xa, xa, true, 10, xb, xa);                  // self: xa -> xb (CS aliases xa)
    ln_k<<<BT_, 256, 0, stream>>>(keyval, lnkv_g, lnkv_b, xa);   // kv0 -> xa
    run_attn(xb, xa, false, 25, xa, xb);                 // cross: -> xa (CS aliases xb)

    add_k<<<1024, 256, 0, stream>>>(xa, res, xb);        // res2 -> xb
    ln_k<<<BT_, 256, 0, stream>>>(xb, lnf_g, lnf_b, res);// ffn input -> res

    shift_lerp_k<<<1024, 256, 0, stream>>>(res, in[40], dd, zb);
    cw(in[41], wscr, 1024, 3584, 1024, 3584);
    mg(zb, wscr, nullptr, kkbb, 3584, 1024, 1024, 3, nullptr, nullptr, nullptr);  // sqrelu key
    cw(in[42], wscr, 3584, 1024, 3584, 1024);
    mg(kkbb, wscr, obf, nullptr, 1024, 3584, 3584, 0, nullptr, nullptr, nullptr); // value
    lerp_dd_k<<<1024, 256, 0, stream>>>(res, dd, in[43], zb);
    cw(in[44], wscr, 1024, 1024, 1024, 1024);
    mg(zb, wscr, vbf, nullptr, 1024, 1024, 1024, 2, nullptr, nullptr, nullptr);   // sigmoid rec
    final_k<<<1024, 256, 0, stream>>>(xb, vbf, obf, out);
}